// Round 3
// baseline (59.032 us; speedup 1.0000x reference)
//
#include <hip/hip_runtime.h>
#include <math.h>

#define EPSF 1e-7f
#define NP   4096    // points per set
#define QPT  16      // queries per thread
#define DSL  128     // db points per LDS subtile

// packed 2xf32 fma: d = a*b + c  (v_pk_fma_f32, default modifiers)
__device__ __forceinline__ float2 pk_fma(float2 a, float2 b, float2 c) {
    float2 d;
    asm("v_pk_fma_f32 %0, %1, %2, %3" : "=v"(d) : "v"(a), "v"(b), "v"(c));
    return d;
}

// ---------------------------------------------------------------------------
// Stage 1: grid = (nslice, 16): x = db slice group, y = dir*8 + batch.
// Block covers ALL 4096 queries of its (dir,b) against a slice of the db.
// LDS db tile is pair-transposed: per db pair i, tileA=(x0,x1,y0,y1) (scaled
// by -2), tileB=(z0,z1,|p0|^2,|p1|^2-layout (z0,z1,w0,w1)). Inner op per
// (2 db, 1 query): 3 v_pk_fma_f32 + 1 v_min3_f32 = 2.0 inst/pair.
// Writes per-query partial min (no |q|^2) to ws[slice][combo][q].
// ---------------------------------------------------------------------------
__global__ __launch_bounds__(256, 2) void chamfer_pk(
    const float* __restrict__ pred, const float* __restrict__ targ,
    float* __restrict__ ws, int subPerBlock)
{
    const int tid   = threadIdx.x;
    const int slice = blockIdx.x;
    const int combo = blockIdx.y;        // dir*8 + b
    const int dir   = combo >> 3;
    const int b     = combo & 7;
    const float* Q = dir ? targ : pred;
    const float* D = dir ? pred : targ;

    __shared__ float tileA[(DSL / 2) * 4];
    __shared__ float tileB[(DSL / 2) * 4];

    float2 Qx[QPT], Qy[QPT], Qz[QPT];
    float mn[QPT];
    const float* Qb = Q + (size_t)b * NP * 3;
#pragma unroll
    for (int k = 0; k < QPT; ++k) {
        const float* qp = Qb + (size_t)(k * 256 + tid) * 3;
        float x = qp[0], y = qp[1], z = qp[2];
        Qx[k] = make_float2(x, x);
        Qy[k] = make_float2(y, y);
        Qz[k] = make_float2(z, z);
        mn[k] = 3.4e38f;
    }

    const float* Db = D + (size_t)b * NP * 3;
    for (int s = 0; s < subPerBlock; ++s) {
        const int pbase = (slice * subPerBlock + s) * DSL;
        if (tid < DSL) {
            const float* dp = Db + (size_t)(pbase + tid) * 3;
            float x = dp[0], y = dp[1], z = dp[2];
            int i = tid >> 1, h = tid & 1;
            tileA[i * 4 + 0 + h] = -2.f * x;
            tileA[i * 4 + 2 + h] = -2.f * y;
            tileB[i * 4 + 0 + h] = -2.f * z;
            tileB[i * 4 + 2 + h] = fmaf(x, x, fmaf(y, y, z * z));
        }
        __syncthreads();
        const float4* tA = (const float4*)tileA;
        const float4* tB = (const float4*)tileB;
#pragma unroll 2
        for (int m = 0; m < DSL / 2; ++m) {
            float4 A = tA[m], B = tB[m];
            float2 X = make_float2(A.x, A.y);
            float2 Y = make_float2(A.z, A.w);
            float2 Z = make_float2(B.x, B.y);
            float2 W = make_float2(B.z, B.w);
#pragma unroll
            for (int k = 0; k < QPT; ++k) {
                float2 t = pk_fma(Qx[k], X, pk_fma(Qy[k], Y, pk_fma(Qz[k], Z, W)));
                mn[k] = fminf(mn[k], fminf(t.x, t.y));   // -> v_min3_f32
            }
        }
        __syncthreads();
    }

    float* w = ws + ((size_t)(slice * 16 + combo) << 12) + tid;
#pragma unroll
    for (int k = 0; k < QPT; ++k) w[k * 256] = mn[k];
}

// ---------------------------------------------------------------------------
// Stage 2: per query, min over slices, + |q|^2, sqrt, block-sum.
// 256 blocks x 256 threads (one query per thread). Writes parts[bid].
// ---------------------------------------------------------------------------
__global__ __launch_bounds__(256) void chamfer_reduce(
    const float* __restrict__ pred, const float* __restrict__ targ,
    const float* __restrict__ ws, float* __restrict__ parts, int nslice)
{
    const int tid = threadIdx.x;
    const int g = blockIdx.x * 256 + tid;
    const int dir = g >> 15, b = (g >> 12) & 7, q = g & 4095;
    const int combo = (dir << 3) | b;

    const float* qp = (dir ? targ : pred) + (size_t)((b << 12) + q) * 3;
    float x = qp[0], y = qp[1], z = qp[2];
    float n1 = fmaf(x, x, fmaf(y, y, z * z));

    float m = 3.4e38f;
    for (int s = 0; s < nslice; ++s)
        m = fminf(m, ws[((size_t)(s * 16 + combo) << 12) + q]);

    float dist = sqrtf(fmaxf(m + n1, 1e-12f));
    for (int off = 32; off; off >>= 1) dist += __shfl_xor(dist, off);
    __shared__ float red[4];
    if ((tid & 63) == 0) red[tid >> 6] = dist;
    __syncthreads();
    if (tid == 0) parts[blockIdx.x] = red[0] + red[1] + red[2] + red[3];
}

// ---------------------------------------------------------------------------
// Finalize: sum 256 chamfer partials + BCE + CR -> scalar.
// ---------------------------------------------------------------------------
__global__ __launch_bounds__(256) void finalize_kernel(
    const float* __restrict__ parts,
    const float* __restrict__ prob_pred, const float* __restrict__ prob_target,
    const float* __restrict__ mu, const float* __restrict__ lb,
    const float* __restrict__ ub,
    float* __restrict__ out, int nprob, int K)
{
    const int tid = threadIdx.x;

    float bce = 0.f;
    const float pmax = 1.0f - EPSF;
    for (int i = tid; i < nprob; i += 256) {
        float p = prob_pred[i];
        p = fminf(fmaxf(p, EPSF), pmax);
        float t = prob_target[i];
        bce += t * logf(p) + (1.0f - t) * log1pf(-p);
    }

    float cr = 0.f;
    const float invK = 1.0f / (float)K;
    for (int i = tid; i < K; i += 256) {
        float c = fabsf(mu[i]) - 0.5f * (lb[i] + ub[i]) + invK;
        cr += fmaxf(c, 0.f);
    }

    float v1 = parts[tid] + cr;
    float v2 = bce;

    for (int off = 32; off; off >>= 1) {
        v1 += __shfl_xor(v1, off);
        v2 += __shfl_xor(v2, off);
    }
    __shared__ float s1[4], s2[4];
    if ((tid & 63) == 0) { s1[tid >> 6] = v1; s2[tid >> 6] = v2; }
    __syncthreads();
    if (tid == 0) {
        float V1 = s1[0] + s1[1] + s1[2] + s1[3];
        float V2 = s2[0] + s2[1] + s2[2] + s2[3];
        out[0] = V1 - V2 / (float)nprob;
    }
}

extern "C" void kernel_launch(void* const* d_in, const int* in_sizes, int n_in,
                              void* d_out, int out_size, void* d_ws, size_t ws_size,
                              hipStream_t stream) {
    const float* prob_pred   = (const float*)d_in[0];
    const float* prob_target = (const float*)d_in[1];
    const float* x_pred      = (const float*)d_in[2];
    const float* x_target    = (const float*)d_in[3];
    const float* mu          = (const float*)d_in[4];
    const float* lb          = (const float*)d_in[5];
    const float* ub          = (const float*)d_in[6];
    float* out = (float*)d_out;
    float* ws  = (float*)d_ws;

    const int K     = in_sizes[4];       // 1000
    const int nprob = in_sizes[0];       // bs*K = 8000

    // pick nslice so ws holds nslice*16*4096 partial mins + 256 parts
    int nslice = 0;
    for (int cand = 32; cand >= 1; cand >>= 1) {
        if (ws_size >= ((size_t)cand * 16 * 4096 + 256) * sizeof(float)) {
            nslice = cand; break;
        }
    }
    if (nslice < 1) nslice = 1;   // ws_size is always >= ~260KB in practice

    dim3 grid1(nslice, 16);
    chamfer_pk<<<grid1, 256, 0, stream>>>(x_pred, x_target, ws, 32 / nslice);
    float* parts = ws + (size_t)nslice * 16 * 4096;
    chamfer_reduce<<<256, 256, 0, stream>>>(x_pred, x_target, ws, parts, nslice);
    finalize_kernel<<<1, 256, 0, stream>>>(parts, prob_pred, prob_target,
                                           mu, lb, ub, out, nprob, K);
}

// Round 4
// 34.549 us; speedup vs baseline: 1.7087x; 1.7087x over previous
//
#include <hip/hip_runtime.h>
#include <math.h>

#define EPSF 1e-7f
#define NP 4096

typedef __attribute__((ext_vector_type(8)))  short  short8;
typedef __attribute__((ext_vector_type(8)))  __bf16 bf16x8;
typedef __attribute__((ext_vector_type(16))) float  f32x16;

__device__ __forceinline__ unsigned short bf16_rn(float x) {
    unsigned int u = __float_as_uint(x);
    unsigned int r = u + 0x7FFFu + ((u >> 16) & 1u);
    return (unsigned short)(r >> 16);
}
__device__ __forceinline__ float bf16_to_f(unsigned short h) {
    return __uint_as_float(((unsigned int)h) << 16);
}

__device__ __forceinline__ void async_copy16(const void* g, void* l) {
    __builtin_amdgcn_global_load_lds(
        (const __attribute__((address_space(1))) unsigned int*)g,
        (__attribute__((address_space(3))) unsigned int*)l, 16, 0, 0);
}

// fold 16 mfma outputs into 2 running-min accumulators (8 v_min3_f32)
__device__ __forceinline__ void fold16(const f32x16& d, float& ra, float& rb) {
    ra = fminf(fminf(d[0],  d[1]),  ra);
    rb = fminf(fminf(d[2],  d[3]),  rb);
    ra = fminf(fminf(d[4],  d[5]),  ra);
    rb = fminf(fminf(d[6],  d[7]),  rb);
    ra = fminf(fminf(d[8],  d[9]),  ra);
    rb = fminf(fminf(d[10], d[11]), rb);
    ra = fminf(fminf(d[12], d[13]), ra);
    rb = fminf(fminf(d[14], d[15]), rb);
}

// query-side (B operand) fragment: kg=0 -> [-2xh,-2yh,-2zh,-2xl,-2yl,-2zl,-2xh,-2yh]
//                                  kg=1 -> [-2zh, 1, 1, 0,0,0,0,0]
__device__ __forceinline__ bf16x8 make_qfrag(float x, float y, float z, int kg) {
    float m2x = -2.f * x, m2y = -2.f * y, m2z = -2.f * z;
    unsigned short xh = bf16_rn(m2x), yh = bf16_rn(m2y), zh = bf16_rn(m2z);
    unsigned short xl = bf16_rn(m2x - bf16_to_f(xh));
    unsigned short yl = bf16_rn(m2y - bf16_to_f(yh));
    unsigned short zl = bf16_rn(m2z - bf16_to_f(zh));
    short8 s;
    if (kg == 0)
        s = short8{(short)xh,(short)yh,(short)zh,(short)xl,(short)yl,(short)zl,(short)xh,(short)yh};
    else
        s = short8{(short)zh,(short)0x3F80,(short)0x3F80,0,0,0,0,0};
    return __builtin_bit_cast(bf16x8, s);
}

// ---------------------------------------------------------------------------
// Build db-side (A operand) panels in frag-ready layout.
// Per point: kg0 = [xh,yh,zh,xh,yh,zh,xl,yl], kg1 = [zl,n2h,n2l,0...] (bf16).
// Panel layout (bytes): (set*8+b)*131072 + tile*1024 + kg*512 + (pt&31)*16.
// ---------------------------------------------------------------------------
__global__ __launch_bounds__(256) void build_panels(
    const float* __restrict__ pred, const float* __restrict__ targ,
    unsigned short* __restrict__ panels)
{
    int g = blockIdx.x * 256 + threadIdx.x;       // 0..65535
    int set = g >> 15, b = (g >> 12) & 7, pt = g & 4095;
    const float* P = (set ? targ : pred) + ((size_t)b * NP + pt) * 3;
    float x = P[0], y = P[1], z = P[2];
    float n2 = fmaf(x, x, fmaf(y, y, z * z));
    unsigned short xh = bf16_rn(x), yh = bf16_rn(y), zh = bf16_rn(z);
    unsigned short xl = bf16_rn(x - bf16_to_f(xh));
    unsigned short yl = bf16_rn(y - bf16_to_f(yh));
    unsigned short zl = bf16_rn(z - bf16_to_f(zh));
    unsigned short nh = bf16_rn(n2);
    unsigned short nl = bf16_rn(n2 - bf16_to_f(nh));
    short8 k0 = short8{(short)xh,(short)yh,(short)zh,(short)xh,(short)yh,(short)zh,(short)xl,(short)yl};
    short8 k1 = short8{(short)zl,(short)nh,(short)nl,0,0,0,0,0};
    char* base = (char*)panels + (size_t)(set * 8 + b) * 131072
               + (size_t)(pt >> 5) * 1024 + (size_t)(pt & 31) * 16;
    *(short8*)base         = k0;
    *(short8*)(base + 512) = k1;
}

// ---------------------------------------------------------------------------
// MFMA chamfer: grid (16 strips, 16 combos, 2 db-halves), 256 thr (4 waves).
// Wave holds 2 query B-frags (64 queries); streams 64 db A-tiles (32 pts each)
// of its half through LDS (double-buffered 2x32KB, global_load_lds w=16).
// Per tile: ds_read_b128 + 2 mfma_32x32x16_bf16 + 16 v_min3.
// Writes per-query partial min (+|q|^2) to wsmin[half][combo][q].
// ---------------------------------------------------------------------------
__global__ __launch_bounds__(256, 2) void chamfer_mfma(
    const float* __restrict__ pred, const float* __restrict__ targ,
    const unsigned short* __restrict__ panels, float* __restrict__ wsmin)
{
    const int tid  = threadIdx.x;
    const int lane = tid & 63, w = tid >> 6;
    const int strip = blockIdx.x;
    const int combo = blockIdx.y;
    const int half  = blockIdx.z;
    const int dir = combo >> 3, b = combo & 7;

    __shared__ char lds[65536];                   // 2 x 32KB double buffer

    // ---- query fragments (B operand) + fp32 norms
    const float* Q = (dir ? targ : pred) + (size_t)b * NP * 3;
    const int kg = lane >> 5;
    const int qA = strip * 256 + w * 64 + (lane & 31);
    const int qB = qA + 32;
    float ax = Q[qA * 3], ay = Q[qA * 3 + 1], az = Q[qA * 3 + 2];
    float bx = Q[qB * 3], by = Q[qB * 3 + 1], bz = Q[qB * 3 + 2];
    bf16x8 fragA = make_qfrag(ax, ay, az, kg);
    bf16x8 fragB = make_qfrag(bx, by, bz, kg);
    const float n1A = fmaf(ax, ax, fmaf(ay, ay, az * az));
    const float n1B = fmaf(bx, by * 0.f + bx * 0.f + bx, 0.f) * 0.f   // (avoid compiler fusing oddly)
                    + fmaf(bx, bx, fmaf(by, by, bz * bz));

    // ---- db panel source for this (dir,b,half): 64 tiles = 2 chunks x 32KB
    const char* panel = (const char*)panels + (size_t)((1 - dir) * 8 + b) * 131072
                      + (size_t)half * 65536;

    float rA0 = 3.4e38f, rA1 = 3.4e38f, rB0 = 3.4e38f, rB1 = 3.4e38f;
    const f32x16 zero = {0.f};

    // prologue: stage chunk 0 into buf 0
#pragma unroll
    for (int i = 0; i < 8; ++i)
        async_copy16(panel + i * 4096 + w * 1024 + lane * 16,
                     lds + i * 4096 + w * 1024);
    __syncthreads();

    // stage chunk 1 into buf 1 (in flight during chunk-0 compute)
#pragma unroll
    for (int i = 0; i < 8; ++i)
        async_copy16(panel + 32768 + i * 4096 + w * 1024 + lane * 16,
                     lds + 32768 + i * 4096 + w * 1024);

#pragma unroll 4
    for (int t = 0; t < 32; ++t) {
        bf16x8 af = *(const bf16x8*)(lds + t * 1024 + kg * 512 + (lane & 31) * 16);
        f32x16 d0 = __builtin_amdgcn_mfma_f32_32x32x16_bf16(af, fragA, zero, 0, 0, 0);
        f32x16 d1 = __builtin_amdgcn_mfma_f32_32x32x16_bf16(af, fragB, zero, 0, 0, 0);
        fold16(d0, rA0, rA1);
        fold16(d1, rB0, rB1);
    }
    __syncthreads();                              // drains chunk-1 loads too

#pragma unroll 4
    for (int t = 0; t < 32; ++t) {
        bf16x8 af = *(const bf16x8*)(lds + 32768 + t * 1024 + kg * 512 + (lane & 31) * 16);
        f32x16 d0 = __builtin_amdgcn_mfma_f32_32x32x16_bf16(af, fragA, zero, 0, 0, 0);
        f32x16 d1 = __builtin_amdgcn_mfma_f32_32x32x16_bf16(af, fragB, zero, 0, 0, 0);
        fold16(d0, rA0, rA1);
        fold16(d1, rB0, rB1);
    }

    float r0 = fminf(rA0, rA1);
    float r1 = fminf(rB0, rB1);
    r0 = fminf(r0, __shfl_xor(r0, 32));           // merge the two row-halves
    r1 = fminf(r1, __shfl_xor(r1, 32));
    float outv = (lane < 32) ? (r0 + n1A) : (r1 + n1B);
    wsmin[(((half << 4) + combo) << 12) + strip * 256 + (w << 6) + lane] = outv;
}

// ---------------------------------------------------------------------------
// Reduce: min over the 2 db-halves, sqrt, block-sum -> parts[256].
// ---------------------------------------------------------------------------
__global__ __launch_bounds__(256) void chamfer_reduce2(
    const float* __restrict__ wsmin, float* __restrict__ parts)
{
    const int tid = threadIdx.x;
    const int g = blockIdx.x * 256 + tid;         // combo*4096 + q
    float m = fminf(wsmin[g], wsmin[65536 + g]);
    float dist = sqrtf(fmaxf(m, 1e-12f));
    for (int off = 32; off; off >>= 1) dist += __shfl_xor(dist, off);
    __shared__ float red[4];
    if ((tid & 63) == 0) red[tid >> 6] = dist;
    __syncthreads();
    if (tid == 0) parts[blockIdx.x] = red[0] + red[1] + red[2] + red[3];
}

// ---------------------------------------------------------------------------
// Finalize: sum 256 chamfer partials + BCE + CR -> scalar.
// ---------------------------------------------------------------------------
__global__ __launch_bounds__(256) void finalize_kernel(
    const float* __restrict__ parts,
    const float* __restrict__ prob_pred, const float* __restrict__ prob_target,
    const float* __restrict__ mu, const float* __restrict__ lb,
    const float* __restrict__ ub,
    float* __restrict__ out, int nprob, int K)
{
    const int tid = threadIdx.x;

    float bce = 0.f;
    const float pmax = 1.0f - EPSF;
    for (int i = tid; i < nprob; i += 256) {
        float p = prob_pred[i];
        p = fminf(fmaxf(p, EPSF), pmax);
        float t = prob_target[i];
        bce += t * logf(p) + (1.0f - t) * log1pf(-p);
    }

    float cr = 0.f;
    const float invK = 1.0f / (float)K;
    for (int i = tid; i < K; i += 256) {
        float c = fabsf(mu[i]) - 0.5f * (lb[i] + ub[i]) + invK;
        cr += fmaxf(c, 0.f);
    }

    float v1 = parts[tid] + cr;
    float v2 = bce;
    for (int off = 32; off; off >>= 1) {
        v1 += __shfl_xor(v1, off);
        v2 += __shfl_xor(v2, off);
    }
    __shared__ float s1[4], s2[4];
    if ((tid & 63) == 0) { s1[tid >> 6] = v1; s2[tid >> 6] = v2; }
    __syncthreads();
    if (tid == 0) {
        float V1 = s1[0] + s1[1] + s1[2] + s1[3];
        float V2 = s2[0] + s2[1] + s2[2] + s2[3];
        out[0] = V1 - V2 / (float)nprob;
    }
}

// ---------------------------------------------------------------------------
// Fallback (tiny ws): monolithic scalar chamfer, 256 partial sums.
// ---------------------------------------------------------------------------
__global__ __launch_bounds__(256) void chamfer_partial_mono(
    const float* __restrict__ pred, const float* __restrict__ targ,
    float* __restrict__ ws)
{
    const int bid = blockIdx.x;
    const int dir = bid >> 7, b = (bid >> 4) & 7, chunk = bid & 15;
    const float* Q = dir ? targ : pred;
    const float* D = dir ? pred : targ;

    __shared__ float4 db[NP];
    const float* Db = D + (size_t)b * NP * 3;
    const int tid = threadIdx.x;
#pragma unroll
    for (int i = 0; i < 16; ++i) {
        int idx = i * 256 + tid;
        float x = Db[idx*3], y = Db[idx*3+1], z = Db[idx*3+2];
        db[idx] = make_float4(-2.f*x, -2.f*y, -2.f*z, fmaf(x,x,fmaf(y,y,z*z)));
    }
    __syncthreads();

    const int qi = chunk * 256 + tid;
    const float* Qp = Q + ((size_t)b * NP + qi) * 3;
    const float qx = Qp[0], qy = Qp[1], qz = Qp[2];
    const float n1 = fmaf(qx,qx,fmaf(qy,qy,qz*qz));

    float m0 = 3.4e38f, m1 = 3.4e38f;
#pragma unroll 4
    for (int m = 0; m < NP; m += 2) {
        float4 a = db[m], c = db[m+1];
        m0 = fminf(m0, fmaf(qx,a.x,fmaf(qy,a.y,fmaf(qz,a.z,a.w))));
        m1 = fminf(m1, fmaf(qx,c.x,fmaf(qy,c.y,fmaf(qz,c.z,c.w))));
    }
    float dist = sqrtf(fmaxf(fminf(m0,m1) + n1, 1e-12f));
    for (int off = 32; off; off >>= 1) dist += __shfl_xor(dist, off);
    __syncthreads();
    float* red = (float*)db;
    if ((tid & 63) == 0) red[tid >> 6] = dist;
    __syncthreads();
    if (tid == 0) ws[bid] = red[0] + red[1] + red[2] + red[3];
}

extern "C" void kernel_launch(void* const* d_in, const int* in_sizes, int n_in,
                              void* d_out, int out_size, void* d_ws, size_t ws_size,
                              hipStream_t stream) {
    const float* prob_pred   = (const float*)d_in[0];
    const float* prob_target = (const float*)d_in[1];
    const float* x_pred      = (const float*)d_in[2];
    const float* x_target    = (const float*)d_in[3];
    const float* mu          = (const float*)d_in[4];
    const float* lb          = (const float*)d_in[5];
    const float* ub          = (const float*)d_in[6];
    float* out = (float*)d_out;

    const int K     = in_sizes[4];    // 1000
    const int nprob = in_sizes[0];    // 8000

    if (ws_size >= (4u << 20)) {
        float* wsmin = (float*)d_ws;                                  // 131072 f32
        float* parts = wsmin + 131072;                                // 256 f32
        unsigned short* panels = (unsigned short*)((char*)d_ws + (1 << 20)); // 2 MB

        build_panels<<<256, 256, 0, stream>>>(x_pred, x_target, panels);
        dim3 grid(16, 16, 2);
        chamfer_mfma<<<grid, 256, 0, stream>>>(x_pred, x_target, panels, wsmin);
        chamfer_reduce2<<<256, 256, 0, stream>>>(wsmin, parts);
        finalize_kernel<<<1, 256, 0, stream>>>(parts, prob_pred, prob_target,
                                               mu, lb, ub, out, nprob, K);
    } else {
        float* ws = (float*)d_ws;
        chamfer_partial_mono<<<256, 256, 0, stream>>>(x_pred, x_target, ws);
        finalize_kernel<<<1, 256, 0, stream>>>(ws, prob_pred, prob_target,
                                               mu, lb, ub, out, nprob, K);
    }
}

// Round 5
// 29.705 us; speedup vs baseline: 1.9873x; 1.1631x over previous
//
#include <hip/hip_runtime.h>
#include <math.h>

#define EPSF 1e-7f
#define NP 4096

typedef __attribute__((ext_vector_type(8)))  short  short8;
typedef __attribute__((ext_vector_type(8)))  __bf16 bf16x8;
typedef __attribute__((ext_vector_type(16))) float  f32x16;

__device__ __forceinline__ unsigned short bf16_rn(float x) {
    unsigned int u = __float_as_uint(x);
    unsigned int r = u + 0x7FFFu + ((u >> 16) & 1u);
    return (unsigned short)(r >> 16);
}
__device__ __forceinline__ float bf16_to_f(unsigned short h) {
    return __uint_as_float(((unsigned int)h) << 16);
}

// fold 16 mfma outputs into 2 running-min accumulators (8 v_min3_f32)
__device__ __forceinline__ void fold16(const f32x16& d, float& ra, float& rb) {
    ra = fminf(fminf(d[0],  d[1]),  ra);
    rb = fminf(fminf(d[2],  d[3]),  rb);
    ra = fminf(fminf(d[4],  d[5]),  ra);
    rb = fminf(fminf(d[6],  d[7]),  rb);
    ra = fminf(fminf(d[8],  d[9]),  ra);
    rb = fminf(fminf(d[10], d[11]), rb);
    ra = fminf(fminf(d[12], d[13]), ra);
    rb = fminf(fminf(d[14], d[15]), rb);
}

// query-side (B operand) fragment (verified round 4, absmax 0.0):
// kg=0 -> [-2xh,-2yh,-2zh,-2xl,-2yl,-2zl,-2xh,-2yh] ; kg=1 -> [-2zh,1,1,0..]
__device__ __forceinline__ bf16x8 make_qfrag(float x, float y, float z, int kg) {
    float m2x = -2.f * x, m2y = -2.f * y, m2z = -2.f * z;
    unsigned short xh = bf16_rn(m2x), yh = bf16_rn(m2y), zh = bf16_rn(m2z);
    unsigned short xl = bf16_rn(m2x - bf16_to_f(xh));
    unsigned short yl = bf16_rn(m2y - bf16_to_f(yh));
    unsigned short zl = bf16_rn(m2z - bf16_to_f(zh));
    short8 s;
    if (kg == 0)
        s = short8{(short)xh,(short)yh,(short)zh,(short)xl,(short)yl,(short)zl,(short)xh,(short)yh};
    else
        s = short8{(short)zh,(short)0x3F80,(short)0x3F80,0,0,0,0,0};
    return __builtin_bit_cast(bf16x8, s);
}

// ---------------------------------------------------------------------------
// Fused chamfer: grid (32 strips, 16 combos) = 512 blocks, 256 thr (4 waves),
// 2 blocks/CU. Each block covers 128 queries (32/wave, one B-frag each) vs the
// FULL 4096-point db of its (dir,b), in two 64KB LDS half-panels built
// in-block from the raw fp32 points (split-bf16 A-frag layout, as round 4).
// Per half: build (8 pts/thread) -> barrier -> 64 x {ds_read_b128 + mfma +
// 8 v_min3} -> barrier.  Epilogue: merge lane^32, +|q|^2, sqrt, wave+block
// sum -> parts[bid].  Deterministic, no atomics.
// ---------------------------------------------------------------------------
__global__ __launch_bounds__(256, 2) void chamfer_all(
    const float* __restrict__ pred, const float* __restrict__ targ,
    float* __restrict__ parts)
{
    const int tid  = threadIdx.x;
    const int lane = tid & 63, w = tid >> 6, kg = lane >> 5;
    const int strip = blockIdx.x;          // 0..31 : 128-query strip
    const int combo = blockIdx.y;          // 0..15 : dir*8 + b
    const int dir = combo >> 3, b = combo & 7;

    __shared__ char  lds[65536];           // one 64KB half-panel
    __shared__ float red[4];

    // ---- query (B operand) fragment + fp32 norm
    const float* Q = (dir ? targ : pred) + (size_t)b * NP * 3;
    const int q = strip * 128 + w * 32 + (lane & 31);
    const float qx = Q[q * 3], qy = Q[q * 3 + 1], qz = Q[q * 3 + 2];
    const bf16x8 frag = make_qfrag(qx, qy, qz, kg);
    const float n1 = fmaf(qx, qx, fmaf(qy, qy, qz * qz));

    const float* D = (dir ? pred : targ) + (size_t)b * NP * 3;

    float r0 = 3.4e38f, r1 = 3.4e38f;
    const f32x16 zero = {0.f};

    for (int half = 0; half < 2; ++half) {
        // ---- build 2048-point half-panel in LDS (A-frag layout, round-4)
#pragma unroll
        for (int i = 0; i < 8; ++i) {
            const int pl = tid + i * 256;               // local 0..2047
            const float* dp = D + (size_t)(half * 2048 + pl) * 3;
            float x = dp[0], y = dp[1], z = dp[2];
            float n2 = fmaf(x, x, fmaf(y, y, z * z));
            unsigned short xh = bf16_rn(x), yh = bf16_rn(y), zh = bf16_rn(z);
            unsigned short xl = bf16_rn(x - bf16_to_f(xh));
            unsigned short yl = bf16_rn(y - bf16_to_f(yh));
            unsigned short zl = bf16_rn(z - bf16_to_f(zh));
            unsigned short nh = bf16_rn(n2);
            unsigned short nl = bf16_rn(n2 - bf16_to_f(nh));
            short8 k0 = short8{(short)xh,(short)yh,(short)zh,
                               (short)xh,(short)yh,(short)zh,
                               (short)xl,(short)yl};
            short8 k1 = short8{(short)zl,(short)nh,(short)nl,0,0,0,0,0};
            char* base = lds + (pl >> 5) * 1024 + (pl & 31) * 16;
            *(short8*)base         = k0;
            *(short8*)(base + 512) = k1;
        }
        __syncthreads();

        // ---- 64 MFMA tiles over this half
#pragma unroll 4
        for (int t = 0; t < 64; ++t) {
            bf16x8 af = *(const bf16x8*)(lds + t * 1024 + kg * 512 + (lane & 31) * 16);
            f32x16 d = __builtin_amdgcn_mfma_f32_32x32x16_bf16(af, frag, zero, 0, 0, 0);
            fold16(d, r0, r1);
        }
        __syncthreads();
    }

    // ---- epilogue: per-query min -> dist -> block sum
    float r = fminf(r0, r1);
    r = fminf(r, __shfl_xor(r, 32));        // merge the two C-row halves
    float dist = sqrtf(fmaxf(r + n1, 1e-12f));
    // lanes L and L^32 now hold identical dist for query (lane&31):
    // butterfly within each 32-lane half sums the 32 distinct queries.
    for (int off = 16; off; off >>= 1) dist += __shfl_xor(dist, off);
    if (lane == 0) red[w] = dist;
    __syncthreads();
    if (tid == 0)
        parts[blockIdx.y * 32 + blockIdx.x] = red[0] + red[1] + red[2] + red[3];
}

// ---------------------------------------------------------------------------
// Finalize: sum 512 chamfer partials + BCE + CR -> scalar.
// ---------------------------------------------------------------------------
__global__ __launch_bounds__(256) void finalize_kernel(
    const float* __restrict__ parts,
    const float* __restrict__ prob_pred, const float* __restrict__ prob_target,
    const float* __restrict__ mu, const float* __restrict__ lb,
    const float* __restrict__ ub,
    float* __restrict__ out, int nprob, int K)
{
    const int tid = threadIdx.x;

    float bce = 0.f;
    const float pmax = 1.0f - EPSF;
    for (int i = tid; i < nprob; i += 256) {
        float p = prob_pred[i];
        p = fminf(fmaxf(p, EPSF), pmax);
        float t = prob_target[i];
        bce += t * logf(p) + (1.0f - t) * log1pf(-p);
    }

    float cr = 0.f;
    const float invK = 1.0f / (float)K;
    for (int i = tid; i < K; i += 256) {
        float c = fabsf(mu[i]) - 0.5f * (lb[i] + ub[i]) + invK;
        cr += fmaxf(c, 0.f);
    }

    float v1 = parts[tid] + parts[tid + 256] + cr;   // 512 partials
    float v2 = bce;
    for (int off = 32; off; off >>= 1) {
        v1 += __shfl_xor(v1, off);
        v2 += __shfl_xor(v2, off);
    }
    __shared__ float s1[4], s2[4];
    if ((tid & 63) == 0) { s1[tid >> 6] = v1; s2[tid >> 6] = v2; }
    __syncthreads();
    if (tid == 0) {
        float V1 = s1[0] + s1[1] + s1[2] + s1[3];
        float V2 = s2[0] + s2[1] + s2[2] + s2[3];
        out[0] = V1 - V2 / (float)nprob;
    }
}

extern "C" void kernel_launch(void* const* d_in, const int* in_sizes, int n_in,
                              void* d_out, int out_size, void* d_ws, size_t ws_size,
                              hipStream_t stream) {
    const float* prob_pred   = (const float*)d_in[0];
    const float* prob_target = (const float*)d_in[1];
    const float* x_pred      = (const float*)d_in[2];
    const float* x_target    = (const float*)d_in[3];
    const float* mu          = (const float*)d_in[4];
    const float* lb          = (const float*)d_in[5];
    const float* ub          = (const float*)d_in[6];
    float* out   = (float*)d_out;
    float* parts = (float*)d_ws;          // 512 floats

    const int K     = in_sizes[4];        // 1000
    const int nprob = in_sizes[0];        // 8000

    dim3 grid(32, 16);
    chamfer_all<<<grid, 256, 0, stream>>>(x_pred, x_target, parts);
    finalize_kernel<<<1, 256, 0, stream>>>(parts, prob_pred, prob_target,
                                           mu, lb, ub, out, nprob, K);
}

// Round 6
// 28.929 us; speedup vs baseline: 2.0406x; 1.0268x over previous
//
#include <hip/hip_runtime.h>
#include <math.h>

#define EPSF 1e-7f
#define NP 4096

typedef __attribute__((ext_vector_type(8)))  short  short8;
typedef __attribute__((ext_vector_type(8)))  __bf16 bf16x8;
typedef __attribute__((ext_vector_type(16))) float  f32x16;

__device__ __forceinline__ unsigned short bf16_rn(float x) {
    unsigned int u = __float_as_uint(x);
    unsigned int r = u + 0x7FFFu + ((u >> 16) & 1u);
    return (unsigned short)(r >> 16);
}
__device__ __forceinline__ float bf16_to_f(unsigned short h) {
    return __uint_as_float(((unsigned int)h) << 16);
}

// fold 16 mfma outputs into 2 running-min accumulators (8 v_min3_f32)
__device__ __forceinline__ void fold16(const f32x16& d, float& ra, float& rb) {
    ra = fminf(fminf(d[0],  d[1]),  ra);
    rb = fminf(fminf(d[2],  d[3]),  rb);
    ra = fminf(fminf(d[4],  d[5]),  ra);
    rb = fminf(fminf(d[6],  d[7]),  rb);
    ra = fminf(fminf(d[8],  d[9]),  ra);
    rb = fminf(fminf(d[10], d[11]), rb);
    ra = fminf(fminf(d[12], d[13]), ra);
    rb = fminf(fminf(d[14], d[15]), rb);
}

// query-side (B operand) fragment (verified rounds 4-5, absmax 0.0):
// kg=0 -> [-2xh,-2yh,-2zh,-2xl,-2yl,-2zl,-2xh,-2yh] ; kg=1 -> [-2zh,1,1,0..]
__device__ __forceinline__ bf16x8 make_qfrag(float x, float y, float z, int kg) {
    float m2x = -2.f * x, m2y = -2.f * y, m2z = -2.f * z;
    unsigned short xh = bf16_rn(m2x), yh = bf16_rn(m2y), zh = bf16_rn(m2z);
    unsigned short xl = bf16_rn(m2x - bf16_to_f(xh));
    unsigned short yl = bf16_rn(m2y - bf16_to_f(yh));
    unsigned short zl = bf16_rn(m2z - bf16_to_f(zh));
    short8 s;
    if (kg == 0)
        s = short8{(short)xh,(short)yh,(short)zh,(short)xl,(short)yl,(short)zl,(short)xh,(short)yh};
    else
        s = short8{(short)zh,(short)0x3F80,(short)0x3F80,0,0,0,0,0};
    return __builtin_bit_cast(bf16x8, s);
}

// ---------------------------------------------------------------------------
// Fused chamfer: grid (16 strips, 16 combos) = 256 blocks (1/CU), 512 threads
// (8 waves), ~130KB LDS. Block builds the FULL 4096-point db panel of its
// (dir,b) in LDS once (split-bf16 A-frag layout). Waves 0-3 scan db-half 0,
// waves 4-7 db-half 1, each wave holding 2 query B-frags (64 queries,
// q = strip*256 + (w&3)*64 + lane). Per tile: 1 ds_read_b128 feeds 2 MFMAs
// (LDS traffic halved vs round 5) with next-tile prefetch. Epilogue merges
// the two halves through LDS, sqrt, deterministic block sum -> parts[bid].
// ---------------------------------------------------------------------------
__global__ __launch_bounds__(512, 2) void chamfer_fused(
    const float* __restrict__ pred, const float* __restrict__ targ,
    float* __restrict__ parts)
{
    const int tid  = threadIdx.x;
    const int lane = tid & 63, w = tid >> 6, kg = lane >> 5;
    const int half = w >> 2;               // which db half this wave scans
    const int strip = blockIdx.x;           // 0..15 : 256-query strip
    const int combo = blockIdx.y;           // 0..15 : dir*8 + b
    const int dir = combo >> 3, b = combo & 7;

    __shared__ char  panel[131072];         // 4096 pts x 32B (128 tiles x 1KB)
    __shared__ float redbuf[512];
    __shared__ float red4[4];

    // ---- query (B operand) fragments + fp32 norms
    const float* Q = (dir ? targ : pred) + (size_t)b * NP * 3;
    const int qA = strip * 256 + (w & 3) * 64 + (lane & 31);
    const int qB = qA + 32;
    const float ax = Q[qA * 3], ay = Q[qA * 3 + 1], az = Q[qA * 3 + 2];
    const float bx = Q[qB * 3], by = Q[qB * 3 + 1], bz = Q[qB * 3 + 2];
    const bf16x8 fragA = make_qfrag(ax, ay, az, kg);
    const bf16x8 fragB = make_qfrag(bx, by, bz, kg);
    const float n1A = fmaf(ax, ax, fmaf(ay, ay, az * az));
    const float n1B = fmaf(bx, bx, fmaf(by, by, bz * bz));

    // ---- build full 4096-point panel in LDS (8 pts/thread)
    const float* D = (dir ? pred : targ) + (size_t)b * NP * 3;
#pragma unroll
    for (int i = 0; i < 8; ++i) {
        const int pt = i * 512 + tid;       // 0..4095
        const float* dp = D + (size_t)pt * 3;
        float x = dp[0], y = dp[1], z = dp[2];
        float n2 = fmaf(x, x, fmaf(y, y, z * z));
        unsigned short xh = bf16_rn(x), yh = bf16_rn(y), zh = bf16_rn(z);
        unsigned short xl = bf16_rn(x - bf16_to_f(xh));
        unsigned short yl = bf16_rn(y - bf16_to_f(yh));
        unsigned short zl = bf16_rn(z - bf16_to_f(zh));
        unsigned short nh = bf16_rn(n2);
        unsigned short nl = bf16_rn(n2 - bf16_to_f(nh));
        short8 k0 = short8{(short)xh,(short)yh,(short)zh,
                           (short)xh,(short)yh,(short)zh,
                           (short)xl,(short)yl};
        short8 k1 = short8{(short)zl,(short)nh,(short)nl,0,0,0,0,0};
        char* base = panel + (pt >> 5) * 1024 + (pt & 31) * 16;
        *(short8*)base         = k0;
        *(short8*)(base + 512) = k1;
    }
    __syncthreads();

    // ---- 64 MFMA tiles over this wave's half, next-tile prefetch
    float rA0 = 3.4e38f, rA1 = 3.4e38f, rB0 = 3.4e38f, rB1 = 3.4e38f;
    const f32x16 zero = {0.f};
    const char* abase = panel + (size_t)half * 65536 + kg * 512 + (lane & 31) * 16;

    bf16x8 af = *(const bf16x8*)(abase);
#pragma unroll 4
    for (int t = 0; t < 63; ++t) {
        bf16x8 afn = *(const bf16x8*)(abase + (t + 1) * 1024);
        f32x16 d0 = __builtin_amdgcn_mfma_f32_32x32x16_bf16(af, fragA, zero, 0, 0, 0);
        f32x16 d1 = __builtin_amdgcn_mfma_f32_32x32x16_bf16(af, fragB, zero, 0, 0, 0);
        fold16(d0, rA0, rA1);
        fold16(d1, rB0, rB1);
        af = afn;
    }
    {
        f32x16 d0 = __builtin_amdgcn_mfma_f32_32x32x16_bf16(af, fragA, zero, 0, 0, 0);
        f32x16 d1 = __builtin_amdgcn_mfma_f32_32x32x16_bf16(af, fragB, zero, 0, 0, 0);
        fold16(d0, rA0, rA1);
        fold16(d1, rB0, rB1);
    }

    // ---- merge C-row halves, add |q|^2, stash per-half per-query d^2
    float rA = fminf(rA0, rA1);  rA = fminf(rA, __shfl_xor(rA, 32));
    float rB = fminf(rB0, rB1);  rB = fminf(rB, __shfl_xor(rB, 32));
    float val = (lane < 32) ? (rA + n1A) : (rB + n1B);   // query strip*256+(w&3)*64+lane
    __syncthreads();                         // panel reads done; reuse-safe
    redbuf[half * 256 + (w & 3) * 64 + lane] = val;
    __syncthreads();

    // ---- min over halves, sqrt, block sum (threads 0..255)
    if (tid < 256) {
        float m = fminf(redbuf[tid], redbuf[256 + tid]);
        float dist = sqrtf(fmaxf(m, 1e-12f));
        for (int off = 32; off; off >>= 1) dist += __shfl_xor(dist, off);
        if ((tid & 63) == 0) red4[tid >> 6] = dist;
    }
    __syncthreads();
    if (tid == 0)
        parts[blockIdx.y * 16 + blockIdx.x] = red4[0] + red4[1] + red4[2] + red4[3];
}

// ---------------------------------------------------------------------------
// Finalize: sum 256 chamfer partials + BCE + CR -> scalar.
// ---------------------------------------------------------------------------
__global__ __launch_bounds__(256) void finalize_kernel(
    const float* __restrict__ parts,
    const float* __restrict__ prob_pred, const float* __restrict__ prob_target,
    const float* __restrict__ mu, const float* __restrict__ lb,
    const float* __restrict__ ub,
    float* __restrict__ out, int nprob, int K)
{
    const int tid = threadIdx.x;

    float bce = 0.f;
    const float pmax = 1.0f - EPSF;
    for (int i = tid; i < nprob; i += 256) {
        float p = prob_pred[i];
        p = fminf(fmaxf(p, EPSF), pmax);
        float t = prob_target[i];
        bce += t * logf(p) + (1.0f - t) * log1pf(-p);
    }

    float cr = 0.f;
    const float invK = 1.0f / (float)K;
    for (int i = tid; i < K; i += 256) {
        float c = fabsf(mu[i]) - 0.5f * (lb[i] + ub[i]) + invK;
        cr += fmaxf(c, 0.f);
    }

    float v1 = parts[tid] + cr;
    float v2 = bce;
    for (int off = 32; off; off >>= 1) {
        v1 += __shfl_xor(v1, off);
        v2 += __shfl_xor(v2, off);
    }
    __shared__ float s1[4], s2[4];
    if ((tid & 63) == 0) { s1[tid >> 6] = v1; s2[tid >> 6] = v2; }
    __syncthreads();
    if (tid == 0) {
        float V1 = s1[0] + s1[1] + s1[2] + s1[3];
        float V2 = s2[0] + s2[1] + s2[2] + s2[3];
        out[0] = V1 - V2 / (float)nprob;
    }
}

extern "C" void kernel_launch(void* const* d_in, const int* in_sizes, int n_in,
                              void* d_out, int out_size, void* d_ws, size_t ws_size,
                              hipStream_t stream) {
    const float* prob_pred   = (const float*)d_in[0];
    const float* prob_target = (const float*)d_in[1];
    const float* x_pred      = (const float*)d_in[2];
    const float* x_target    = (const float*)d_in[3];
    const float* mu          = (const float*)d_in[4];
    const float* lb          = (const float*)d_in[5];
    const float* ub          = (const float*)d_in[6];
    float* out   = (float*)d_out;
    float* parts = (float*)d_ws;          // 256 floats

    const int K     = in_sizes[4];        // 1000
    const int nprob = in_sizes[0];        // 8000

    dim3 grid(16, 16);
    chamfer_fused<<<grid, 512, 0, stream>>>(x_pred, x_target, parts);
    finalize_kernel<<<1, 256, 0, stream>>>(parts, prob_pred, prob_target,
                                           mu, lb, ub, out, nprob, K);
}